// Round 5
// baseline (564.177 us; speedup 1.0000x reference)
//
#include <hip/hip_runtime.h>
#include <hip/hip_bf16.h>
#include <cstdint>
#include <cstddef>

using bf16 = __hip_bfloat16;
typedef __attribute__((ext_vector_type(8))) short short8v;   // MFMA A/B frag: 8 bf16
typedef __attribute__((ext_vector_type(4))) short short4v;   // 4 bf16 (b64 store)
typedef __attribute__((ext_vector_type(4))) float float4v;   // MFMA C/D frag

__device__ inline float b2f(short s) {
  union { float f; uint32_t u; } z; z.u = ((uint32_t)(uint16_t)s) << 16; return z.f;
}
__device__ inline short f2b(float f) {
  bf16 h = __float2bfloat16(f);
  return *reinterpret_cast<short*>(&h);
}

typedef const __attribute__((address_space(1))) uint32_t* gas1p;
typedef __attribute__((address_space(3))) uint32_t* las3p;
__device__ inline void gload_lds16(const void* g, void* l) {
  __builtin_amdgcn_global_load_lds((gas1p)g, (las3p)l, 16, 0, 0);
}

// ---------------------------------------------------------------------------
// GEMM: C[M,N] = A[M,K] @ Bt[N,K]^T + bias(fp32), optional ReLU.
// m97 structure: 128x128 tile, BK=32, 4 waves, 4x4 mfma_f32_16x16x32_bf16,
// global_load_lds width-16 staging. M,N % 128 == 0, K % 32 == 0.
// ---------------------------------------------------------------------------
__global__ __launch_bounds__(256) void gemm_bt(
    const bf16* __restrict__ A, const bf16* __restrict__ Bt,
    const float* __restrict__ bias, void* __restrict__ C,
    int M, int N, int K, int ldc, int relu_mode, int out_f32) {
  __shared__ __align__(16) bf16 As[128 * 32];
  __shared__ __align__(16) bf16 Bs[128 * 32];
  const int tid = threadIdx.x;
  const int w = tid >> 6, lane = tid & 63;
  const int quad = lane >> 4, l16 = lane & 15;
  const int wrow = (w >> 1) * 64, wcol = (w & 1) * 64;
  const int mbase = blockIdx.y * 128, nbase = blockIdx.x * 128;
  const int c = w * 128 + lane;            // chunk ids c and c+64
  const int row0 = c >> 2, p0 = c & 3;
  const int row1 = (c + 64) >> 2, p1 = (c + 64) & 3;

  float4v acc[4][4];
  for (int i = 0; i < 4; i++)
    for (int j = 0; j < 4; j++) acc[i][j] = (float4v){0.f, 0.f, 0.f, 0.f};

  for (int k0 = 0; k0 < K; k0 += 32) {
    __syncthreads();  // prev iter's ds_reads done before restage
    gload_lds16(A + (size_t)(mbase + row0) * K + k0 + p0 * 8, (char*)As + w * 2048);
    gload_lds16(A + (size_t)(mbase + row1) * K + k0 + p1 * 8, (char*)As + w * 2048 + 1024);
    gload_lds16(Bt + (size_t)(nbase + row0) * K + k0 + p0 * 8, (char*)Bs + w * 2048);
    gload_lds16(Bt + (size_t)(nbase + row1) * K + k0 + p1 * 8, (char*)Bs + w * 2048 + 1024);
    __syncthreads();  // vmcnt drained -> tiles valid

    short8v a[4], b[4];
    for (int mt = 0; mt < 4; mt++)
      a[mt] = *reinterpret_cast<const short8v*>(As + (wrow + mt * 16 + l16) * 32 + quad * 8);
    for (int nt = 0; nt < 4; nt++)
      b[nt] = *reinterpret_cast<const short8v*>(Bs + (wcol + nt * 16 + l16) * 32 + quad * 8);
    for (int mt = 0; mt < 4; mt++)
      for (int nt = 0; nt < 4; nt++)
        acc[mt][nt] = __builtin_amdgcn_mfma_f32_16x16x32_bf16(a[mt], b[nt], acc[mt][nt], 0, 0, 0);
  }

  // epilogue: D row = quad*4+reg, col = lane&15
  for (int nt = 0; nt < 4; nt++) {
    int col = nbase + wcol + nt * 16 + l16;
    float bv = bias[col];
    for (int mt = 0; mt < 4; mt++) {
      int row = mbase + wrow + mt * 16 + quad * 4;
      for (int r = 0; r < 4; r++) {
        float v = acc[mt][nt][r] + bv;
        if (relu_mode) v = fmaxf(v, 0.f);
        size_t idx = (size_t)(row + r) * ldc + col;
        if (out_f32) ((float*)C)[idx] = v;
        else         ((short*)C)[idx] = f2b(v);
      }
    }
  }
}

// ---------------------------------------------------------------------------
// Flash attention v3. Same math as v2 (S^T = K·Q^T, no-max exp softmax,
// wave-private P round trip, 1-barrier double-buffered Vt) with:
//  - 16 q rows/wave, grid (32,32) = 1024 blocks -> 4 blocks/CU (occupancy
//    cap 50%, was grid-limited at 25%).
//  - pointer-increment addressing: kv0 += 32 advances K/V/mask pointers by a
//    constant (6144 elem = 2 rows of [4096,3072]); kills per-iter addr VALU.
// ---------------------------------------------------------------------------
__global__ __launch_bounds__(256) void attn_kernel(
    const bf16* __restrict__ qkv, const int* __restrict__ mask,
    bf16* __restrict__ ao) {
  __shared__ __align__(16) short Vt[2][64 * 40];   // [buf][d][kv], pitch 40
  __shared__ __align__(16) short Pbuf[4][16 * 40]; // per-wave [q][kv], pitch 40

  const int tid = threadIdx.x;
  const int w = tid >> 6, lane = tid & 63;
  const int quad = lane >> 4, l16 = lane & 15;
  const int bh = blockIdx.y, b = bh >> 4;
  const int row0 = bh * 128;                 // row base in qkv [4096,3072]
  const int qbase = blockIdx.x * 64 + w * 16;   // wave's 16 q rows
  const int vr = tid & 31, vdb = (tid >> 5) * 8;

  // Q frags (B-operand of S^T): n=q=l16, k=d=quad*8+j
  short8v aq[2];
  for (int dh = 0; dh < 2; dh++) {
    int local = (qbase + l16) * 64 + dh * 32 + quad * 8;
    aq[dh] = *reinterpret_cast<const short8v*>(
        qkv + (size_t)(row0 + (local >> 10)) * 3072 + (local & 1023));
  }

  // K frag pointers (A-operand of S^T): m=kv=s*16+l16, k=d=dh*32+quad*8
  const bf16* pk[2][2];
  for (int s = 0; s < 2; s++)
    for (int dh = 0; dh < 2; dh++) {
      int local = (s * 16 + l16) * 64 + dh * 32 + quad * 8;
      pk[s][dh] = qkv + (size_t)(row0 + (local >> 10)) * 3072 + (local & 1023) + 1024;
    }
  const bf16* pv;
  {
    int local = vr * 64 + vdb;
    pv = qkv + (size_t)(row0 + (local >> 10)) * 3072 + (local & 1023) + 2048;
  }
  const int* pm = mask + b * 2048 + quad * 4;

  float4v o[4];
  for (int nt = 0; nt < 4; nt++) o[nt] = (float4v){0.f, 0.f, 0.f, 0.f};
  float lsum = 0.f;

  for (int it = 0; it < 64; it++) {
    const int pb = it & 1;
    // stage V^T tile (1 b128 global load + 8 b16 LDS writes per thread)
    {
      short8v vv = *reinterpret_cast<const short8v*>(pv);
      short* vt = &Vt[pb][0];
      for (int j = 0; j < 8; j++) vt[(vdb + j) * 40 + vr] = vv[j];
    }
    short8v ak[2][2];
    for (int s = 0; s < 2; s++)
      for (int dh = 0; dh < 2; dh++)
        ak[s][dh] = *reinterpret_cast<const short8v*>(pk[s][dh]);
    int4 mv0 = *reinterpret_cast<const int4*>(pm);
    int4 mv1 = *reinterpret_cast<const int4*>(pm + 16);
    pv += 6144;
    pk[0][0] += 6144; pk[0][1] += 6144; pk[1][0] += 6144; pk[1][1] += 6144;
    pm += 32;
    __syncthreads();  // Vt[pb] valid; prev-iter reads (other buffer) retired

    // S^T tiles: rows kv=s*16+quad*4+r, cols q=l16
    float4v st[2];
    for (int s = 0; s < 2; s++) {
      float4v t = (float4v){0.f, 0.f, 0.f, 0.f};
      t = __builtin_amdgcn_mfma_f32_16x16x32_bf16(ak[s][0], aq[0], t, 0, 0, 0);
      t = __builtin_amdgcn_mfma_f32_16x16x32_bf16(ak[s][1], aq[1], t, 0, 0, 0);
      st[s] = t;
    }

    // p = exp(clamped, masked score); per-lane l partial; b64 to Pbuf
    for (int s = 0; s < 2; s++) {
      int mm[4] = {s ? mv1.x : mv0.x, s ? mv1.y : mv0.y,
                   s ? mv1.z : mv0.z, s ? mv1.w : mv0.w};
      short4v pkv;
      for (int r = 0; r < 4; r++) {
        float xx = st[s][r] * 0.125f;              // / sqrt(64)
        xx = fminf(fmaxf(xx, -30.f), 30.f);
        xx = (mm[r] == 0) ? -1e-12f : xx;          // faithful mask semantics
        float e = __expf(xx);
        lsum += e;
        pkv[r] = f2b(e);
      }
      *reinterpret_cast<short4v*>(&Pbuf[w][l16 * 40 + s * 16 + quad * 4]) = pkv;
    }
    // same-wave LDS round trip (DS in-order within a wave): no barrier
    short8v pf = *reinterpret_cast<const short8v*>(&Pbuf[w][l16 * 40 + quad * 8]);
    for (int nt = 0; nt < 4; nt++) {
      short8v bv = *reinterpret_cast<const short8v*>(&Vt[pb][(nt * 16 + l16) * 40 + quad * 8]);
      o[nt] = __builtin_amdgcn_mfma_f32_16x16x32_bf16(pf, bv, o[nt], 0, 0, 0);
    }
  }

  // lsum holds partial for q=l16 over this quad's kv rows; reduce across quads
  lsum += __shfl_xor(lsum, 16);
  lsum += __shfl_xor(lsum, 32);
  // epilogue: lane holds q=quad*4+r, d=nt*16+l16
  for (int r = 0; r < 4; r++) {
    float linv = 1.0f / __shfl(lsum, quad * 4 + r);
    int qg = qbase + quad * 4 + r;
    for (int nt = 0; nt < 4; nt++) {
      int d = nt * 16 + l16;
      ao[(size_t)bh * 131072 + (size_t)qg * 64 + d] = __float2bfloat16(o[nt][r] * linv);
    }
  }
}

// ---------------------------------------------------------------------------
// out = LN(a + xres); unbiased std (ddof=1), /(std + 1e-12). One block / row.
// Per-operand dtype flags (fp32 or bf16). gamma/beta fp32. fp32 math.
// Safe for out == a (reads precede barrier; writes follow).
// ---------------------------------------------------------------------------
__global__ __launch_bounds__(256) void ln_resid(
    const void* __restrict__ a, const void* __restrict__ xres,
    const float* __restrict__ gamma, const float* __restrict__ beta,
    void* __restrict__ out, int a_f32, int x_f32, int out_f32) {
  __shared__ float red[8];
  const int row = blockIdx.x, tid = threadIdx.x;
  const int w = tid >> 6, lane = tid & 63;
  const size_t base = (size_t)row * 1024;
  float v[4]; float sum = 0.f, ss = 0.f;
  for (int i = 0; i < 4; i++) {
    int c = tid + i * 256;
    float av = a_f32 ? ((const float*)a)[base + c] : b2f(((const short*)a)[base + c]);
    float xv = x_f32 ? ((const float*)xres)[base + c] : b2f(((const short*)xres)[base + c]);
    v[i] = av + xv;
    sum += v[i]; ss += v[i] * v[i];
  }
  for (int off = 1; off < 64; off <<= 1) {
    sum += __shfl_xor(sum, off);
    ss  += __shfl_xor(ss, off);
  }
  if (lane == 0) { red[w * 2] = sum; red[w * 2 + 1] = ss; }
  __syncthreads();
  sum = red[0] + red[2] + red[4] + red[6];
  ss  = red[1] + red[3] + red[5] + red[7];
  float mean = sum * (1.0f / 1024.0f);
  float var = (ss - 1024.0f * mean * mean) * (1.0f / 1023.0f);
  var = fmaxf(var, 0.f);
  float rden = 1.0f / (sqrtf(var) + 1e-12f);
  for (int i = 0; i < 4; i++) {
    int c = tid + i * 256;
    float y = gamma[c] * ((v[i] - mean) * rden) + beta[c];
    if (out_f32) ((float*)out)[base + c] = y;
    else         ((short*)out)[base + c] = f2b(y);
  }
}

// out(bf16)[c*R + r] = in(f32)[r*C + c]; R,C % 32 == 0. block (32,8),
// grid (C/32, R/32).
__global__ __launch_bounds__(256) void transpose_k(
    const float* __restrict__ in, bf16* __restrict__ out, int R, int C) {
  __shared__ short t[32][33];
  const int tx = threadIdx.x, ty = threadIdx.y;
  const int cb = blockIdx.x * 32, rb = blockIdx.y * 32;
  for (int j = 0; j < 4; j++)
    t[ty + j * 8][tx] = f2b(in[(size_t)(rb + ty + j * 8) * C + cb + tx]);
  __syncthreads();
  for (int j = 0; j < 4; j++)
    ((short*)out)[(size_t)(cb + ty + j * 8) * R + rb + tx] = t[tx][ty + j * 8];
}

__global__ __launch_bounds__(256) void concat3(
    const float* __restrict__ a, const float* __restrict__ b,
    const float* __restrict__ c, float* __restrict__ out) {
  int i = blockIdx.x * 256 + threadIdx.x;  // grid 12 -> 3072
  float v;
  if (i < 1024)       v = a[i];
  else if (i < 2048)  v = b[i - 1024];
  else                v = c[i - 2048];
  out[i] = v;
}

// fp32 -> bf16 elementwise cast, 4 elems/thread, n % 1024 == 0.
__global__ __launch_bounds__(256) void cast_f32_bf16(
    const float* __restrict__ in, bf16* __restrict__ out) {
  int i0 = (blockIdx.x * 256 + threadIdx.x) * 4;
  float4 f = *reinterpret_cast<const float4*>(in + i0);
  short* o = (short*)out + i0;
  o[0] = f2b(f.x); o[1] = f2b(f.y); o[2] = f2b(f.z); o[3] = f2b(f.w);
}

// ---------------------------------------------------------------------------
extern "C" void kernel_launch(void* const* d_in, const int* in_sizes, int n_in,
                              void* d_out, int out_size, void* d_ws, size_t ws_size,
                              hipStream_t stream) {
  (void)in_sizes; (void)n_in; (void)out_size; (void)ws_size;
  const float* x    = (const float*)d_in[0];
  const int*   mask = (const int*)d_in[1];
  const float* wq_w = (const float*)d_in[2];
  const float* wq_b = (const float*)d_in[3];
  const float* wk_w = (const float*)d_in[4];
  const float* wk_b = (const float*)d_in[5];
  const float* wv_w = (const float*)d_in[6];
  const float* wv_b = (const float*)d_in[7];
  const float* wo_w = (const float*)d_in[8];
  const float* wo_b = (const float*)d_in[9];
  const float* g1   = (const float*)d_in[10];
  const float* be1  = (const float*)d_in[11];
  const float* f1w  = (const float*)d_in[12];
  const float* f1b  = (const float*)d_in[13];
  const float* f2w  = (const float*)d_in[14];
  const float* f2b_ = (const float*)d_in[15];
  const float* g2   = (const float*)d_in[16];
  const float* be2  = (const float*)d_in[17];
  float* out = (float*)d_out;
  char* ws = (char*)d_ws;

  // ws layout (peak 48 MiB, time-shared):
  //  [0,24M)   QKV (ph2-3) -> PROJ [0,8M) (ph4-5) -> H [0,32M) (ph6-7)
  //  [24M,32M) Xbf (ph1-2) -> AO (ph3-4)
  //  [32M,40M) X1  (ph5-8)
  //  [40M,48M) WT  (transposed weights, per-phase)  + BQKV fp32 tail
  bf16*  QKV  = (bf16*)(ws + 0);
  bf16*  Xbf  = (bf16*)(ws + 25165824);
  bf16*  AO   = (bf16*)(ws + 25165824);
  bf16*  PROJ = (bf16*)(ws + 0);
  bf16*  H    = (bf16*)(ws + 0);
  bf16*  X1   = (bf16*)(ws + 33554432);
  bf16*  WT   = (bf16*)(ws + 41943040);
  float* BQKV = (float*)(ws + 48234496);

  dim3 tb(32, 8);
  // phase 1: casts + QKV weights
  cast_f32_bf16<<<dim3(4096), dim3(256), 0, stream>>>(x, Xbf);
  transpose_k<<<dim3(32, 32), tb, 0, stream>>>(wq_w, WT, 1024, 1024);
  transpose_k<<<dim3(32, 32), tb, 0, stream>>>(wk_w, WT + 1024 * 1024, 1024, 1024);
  transpose_k<<<dim3(32, 32), tb, 0, stream>>>(wv_w, WT + 2 * 1024 * 1024, 1024, 1024);
  concat3<<<dim3(12), dim3(256), 0, stream>>>(wq_b, wk_b, wv_b, BQKV);
  // phase 2: fused QKV projection [4096,1024]@[3072,1024]^T -> bf16
  gemm_bt<<<dim3(24, 32), dim3(256), 0, stream>>>(Xbf, WT, BQKV, QKV, 4096, 3072, 1024, 3072, 0, 0);
  // phase 3: attention (1024 blocks: 32 q-blocks x 32 bh)
  attn_kernel<<<dim3(32, 32), dim3(256), 0, stream>>>(QKV, mask, AO);
  // phase 4: output projection
  transpose_k<<<dim3(32, 32), tb, 0, stream>>>(wo_w, WT, 1024, 1024);
  gemm_bt<<<dim3(8, 32), dim3(256), 0, stream>>>(AO, WT, wo_b, PROJ, 4096, 1024, 1024, 1024, 0, 0);
  // phase 5: LN1 (xres = original fp32 x)
  ln_resid<<<dim3(4096), dim3(256), 0, stream>>>(PROJ, x, g1, be1, X1, 0, 1, 0);
  // phase 6: FFN up
  transpose_k<<<dim3(128, 32), tb, 0, stream>>>(f1w, WT, 1024, 4096);
  gemm_bt<<<dim3(32, 32), dim3(256), 0, stream>>>(X1, WT, f1b, H, 4096, 4096, 1024, 4096, 1, 0);
  // phase 7: FFN down, fp32 straight into d_out
  transpose_k<<<dim3(32, 128), tb, 0, stream>>>(f2w, WT, 4096, 1024);
  gemm_bt<<<dim3(8, 32), dim3(256), 0, stream>>>(H, WT, f2b_, out, 4096, 1024, 4096, 1024, 0, 1);
  // phase 8: LN2 in-place on d_out (fp32 a, bf16 xres, fp32 out)
  ln_resid<<<dim3(4096), dim3(256), 0, stream>>>(out, X1, g2, be2, out, 1, 0, 1);
}

// Round 7
// 474.096 us; speedup vs baseline: 1.1900x; 1.1900x over previous
//
#include <hip/hip_runtime.h>
#include <hip/hip_bf16.h>
#include <cstdint>
#include <cstddef>

using bf16 = __hip_bfloat16;
typedef __attribute__((ext_vector_type(8))) short short8v;   // MFMA A/B frag: 8 bf16
typedef __attribute__((ext_vector_type(4))) short short4v;   // 4 bf16 (b64 store)
typedef __attribute__((ext_vector_type(4))) float float4v;   // MFMA C/D frag

__device__ inline float b2f(short s) {
  union { float f; uint32_t u; } z; z.u = ((uint32_t)(uint16_t)s) << 16; return z.f;
}
__device__ inline short f2b(float f) {
  bf16 h = __float2bfloat16(f);
  return *reinterpret_cast<short*>(&h);
}

typedef const __attribute__((address_space(1))) uint32_t* gas1p;
typedef __attribute__((address_space(3))) uint32_t* las3p;
__device__ inline void gload_lds16(const void* g, void* l) {
  __builtin_amdgcn_global_load_lds((gas1p)g, (las3p)l, 16, 0, 0);
}

// ---------------------------------------------------------------------------
// GEMM: C[M,N] = A[M,K] @ Bt[N,K]^T + bias(fp32), optional ReLU.
// m97 structure: 128x128 tile, BK=32, 4 waves, 4x4 mfma_f32_16x16x32_bf16,
// global_load_lds width-16 staging. M,N % 128 == 0, K % 32 == 0.
// ---------------------------------------------------------------------------
__global__ __launch_bounds__(256) void gemm_bt(
    const bf16* __restrict__ A, const bf16* __restrict__ Bt,
    const float* __restrict__ bias, void* __restrict__ C,
    int M, int N, int K, int ldc, int relu_mode, int out_f32) {
  __shared__ __align__(16) bf16 As[128 * 32];
  __shared__ __align__(16) bf16 Bs[128 * 32];
  const int tid = threadIdx.x;
  const int w = tid >> 6, lane = tid & 63;
  const int quad = lane >> 4, l16 = lane & 15;
  const int wrow = (w >> 1) * 64, wcol = (w & 1) * 64;
  const int mbase = blockIdx.y * 128, nbase = blockIdx.x * 128;
  const int c = w * 128 + lane;            // chunk ids c and c+64
  const int row0 = c >> 2, p0 = c & 3;
  const int row1 = (c + 64) >> 2, p1 = (c + 64) & 3;

  float4v acc[4][4];
  for (int i = 0; i < 4; i++)
    for (int j = 0; j < 4; j++) acc[i][j] = (float4v){0.f, 0.f, 0.f, 0.f};

  for (int k0 = 0; k0 < K; k0 += 32) {
    __syncthreads();  // prev iter's ds_reads done before restage
    gload_lds16(A + (size_t)(mbase + row0) * K + k0 + p0 * 8, (char*)As + w * 2048);
    gload_lds16(A + (size_t)(mbase + row1) * K + k0 + p1 * 8, (char*)As + w * 2048 + 1024);
    gload_lds16(Bt + (size_t)(nbase + row0) * K + k0 + p0 * 8, (char*)Bs + w * 2048);
    gload_lds16(Bt + (size_t)(nbase + row1) * K + k0 + p1 * 8, (char*)Bs + w * 2048 + 1024);
    __syncthreads();  // vmcnt drained -> tiles valid

    short8v a[4], b[4];
    for (int mt = 0; mt < 4; mt++)
      a[mt] = *reinterpret_cast<const short8v*>(As + (wrow + mt * 16 + l16) * 32 + quad * 8);
    for (int nt = 0; nt < 4; nt++)
      b[nt] = *reinterpret_cast<const short8v*>(Bs + (wcol + nt * 16 + l16) * 32 + quad * 8);
    for (int mt = 0; mt < 4; mt++)
      for (int nt = 0; nt < 4; nt++)
        acc[mt][nt] = __builtin_amdgcn_mfma_f32_16x16x32_bf16(a[mt], b[nt], acc[mt][nt], 0, 0, 0);
  }

  // epilogue: D row = quad*4+reg, col = lane&15
  for (int nt = 0; nt < 4; nt++) {
    int col = nbase + wcol + nt * 16 + l16;
    float bv = bias[col];
    for (int mt = 0; mt < 4; mt++) {
      int row = mbase + wrow + mt * 16 + quad * 4;
      for (int r = 0; r < 4; r++) {
        float v = acc[mt][nt][r] + bv;
        if (relu_mode) v = fmaxf(v, 0.f);
        size_t idx = (size_t)(row + r) * ldc + col;
        if (out_f32) ((float*)C)[idx] = v;
        else         ((short*)C)[idx] = f2b(v);
      }
    }
  }
}

// ---------------------------------------------------------------------------
// Flash attention v4 = v2 shape (32 q-rows/wave, 512 blocks — best measured)
// + v3 pointer-increment addressing + SOFTWARE PIPELINE:
//   iter i prefetches K/V/mask for i+1 into regs at the top, consumes K from
//   regs, computes, then stages the prefetched V into the other Vt buffer at
//   the END of the iter. One barrier per iter. Global-load latency (the
//   measured ~2k-cycle/iter stall) overlaps the compute phase.
// ---------------------------------------------------------------------------
__global__ __launch_bounds__(256) void attn_kernel(
    const bf16* __restrict__ qkv, const int* __restrict__ mask,
    bf16* __restrict__ ao) {
  __shared__ __align__(16) short Vt[2][64 * 40];   // [buf][d][kv], pitch 40
  __shared__ __align__(16) short Pbuf[4][32 * 40]; // per-wave [q][kv], pitch 40

  const int tid = threadIdx.x;
  const int w = tid >> 6, lane = tid & 63;
  const int quad = lane >> 4, l16 = lane & 15;
  const int bh = blockIdx.y, b = bh >> 4;
  const int row0 = bh * 128;                 // row base in qkv [4096,3072]
  const int qbase = blockIdx.x * 128 + w * 32;  // wave's 32 q rows
  const int vr = tid & 31, vdb = (tid >> 5) * 8;

  // Q frags (B-operand of S^T): n=q=h*16+l16, k=d=dh*32+quad*8
  short8v aq[2][2];
  for (int h = 0; h < 2; h++)
    for (int dh = 0; dh < 2; dh++) {
      int local = (qbase + h * 16 + l16) * 64 + dh * 32 + quad * 8;
      aq[h][dh] = *reinterpret_cast<const short8v*>(
          qkv + (size_t)(row0 + (local >> 10)) * 3072 + (local & 1023));
    }

  // K frag pointers (A-operand of S^T): m=kv=s*16+l16, k=d=dh*32+quad*8
  const bf16* pk[2][2];
  for (int s = 0; s < 2; s++)
    for (int dh = 0; dh < 2; dh++) {
      int local = (s * 16 + l16) * 64 + dh * 32 + quad * 8;
      pk[s][dh] = qkv + (size_t)(row0 + (local >> 10)) * 3072 + (local & 1023) + 1024;
    }
  const bf16* pv;
  {
    int local = vr * 64 + vdb;
    pv = qkv + (size_t)(row0 + (local >> 10)) * 3072 + (local & 1023) + 2048;
  }
  const int* pm = mask + b * 2048 + quad * 4;

  float4v o[2][4];
  for (int h = 0; h < 2; h++)
    for (int nt = 0; nt < 4; nt++) o[h][nt] = (float4v){0.f, 0.f, 0.f, 0.f};
  float lsum[2] = {0.f, 0.f};

  // prologue: operands for iter 0
  short8v kcur[2][2], vcur;
  vcur = *reinterpret_cast<const short8v*>(pv);
  for (int s = 0; s < 2; s++)
    for (int dh = 0; dh < 2; dh++)
      kcur[s][dh] = *reinterpret_cast<const short8v*>(pk[s][dh]);
  int4 mc0 = *reinterpret_cast<const int4*>(pm);
  int4 mc1 = *reinterpret_cast<const int4*>(pm + 16);
  pv += 6144; pm += 32;
  for (int s = 0; s < 2; s++)
    for (int dh = 0; dh < 2; dh++) pk[s][dh] += 6144;
  {
    short* vt = &Vt[0][0];
    for (int j = 0; j < 8; j++) vt[(vdb + j) * 40 + vr] = vcur[j];
  }
  __syncthreads();

  for (int it = 0; it < 64; it++) {
    const int pb = it & 1;
    // prefetch iter it+1 (full compute phase to cover the latency)
    short8v knext[2][2], vnext;
    int4 mn0, mn1;
    if (it < 63) {
      vnext = *reinterpret_cast<const short8v*>(pv);
      for (int s = 0; s < 2; s++)
        for (int dh = 0; dh < 2; dh++)
          knext[s][dh] = *reinterpret_cast<const short8v*>(pk[s][dh]);
      mn0 = *reinterpret_cast<const int4*>(pm);
      mn1 = *reinterpret_cast<const int4*>(pm + 16);
      pv += 6144; pm += 32;
      for (int s = 0; s < 2; s++)
        for (int dh = 0; dh < 2; dh++) pk[s][dh] += 6144;
    }

    // S^T tiles from registers: rows kv=s*16+quad*4+r, cols q=h*16+l16
    float4v st[2][2];
    for (int s = 0; s < 2; s++)
      for (int h = 0; h < 2; h++) {
        float4v t = (float4v){0.f, 0.f, 0.f, 0.f};
        t = __builtin_amdgcn_mfma_f32_16x16x32_bf16(kcur[s][0], aq[h][0], t, 0, 0, 0);
        t = __builtin_amdgcn_mfma_f32_16x16x32_bf16(kcur[s][1], aq[h][1], t, 0, 0, 0);
        st[s][h] = t;
      }

    // p = exp(score/8) via exp2 with folded log2(e); per-lane l partial
    for (int h = 0; h < 2; h++)
      for (int s = 0; s < 2; s++) {
        int4 mv = s ? mc1 : mc0;
        int mm[4] = {mv.x, mv.y, mv.z, mv.w};
        short4v pkv;
        for (int r = 0; r < 4; r++) {
          float y = st[s][h][r] * 0.180336880f;     // (1/8)*log2(e)
          y = fminf(fmaxf(y, -43.3f), 43.3f);       // garbage guard only
          y = (mm[r] == 0) ? -1.4427e-12f : y;      // faithful mask semantics
          float e = __builtin_amdgcn_exp2f(y);
          lsum[h] += e;
          pkv[r] = f2b(e);
        }
        *reinterpret_cast<short4v*>(&Pbuf[w][(h * 16 + l16) * 40 + s * 16 + quad * 4]) = pkv;
      }
    // same-wave LDS round trip (DS in-order within a wave): no barrier
    short8v pf[2];
    for (int h = 0; h < 2; h++)
      pf[h] = *reinterpret_cast<const short8v*>(&Pbuf[w][(h * 16 + l16) * 40 + quad * 8]);
    for (int nt = 0; nt < 4; nt++) {
      short8v bv = *reinterpret_cast<const short8v*>(&Vt[pb][(nt * 16 + l16) * 40 + quad * 8]);
      for (int h = 0; h < 2; h++)
        o[h][nt] = __builtin_amdgcn_mfma_f32_16x16x32_bf16(pf[h], bv, o[h][nt], 0, 0, 0);
    }

    // stage next V tile (prefetched regs) into the other buffer
    if (it < 63) {
      short* vt = &Vt[1 - pb][0];
      for (int j = 0; j < 8; j++) vt[(vdb + j) * 40 + vr] = vnext[j];
      for (int s = 0; s < 2; s++)
        for (int dh = 0; dh < 2; dh++) kcur[s][dh] = knext[s][dh];
      mc0 = mn0; mc1 = mn1;
    }
    __syncthreads();  // Vt[1-pb] valid for it+1; Vt[pb] reads retired
  }

  // l: reduce across quads, then divide and store
  for (int h = 0; h < 2; h++) {
    lsum[h] += __shfl_xor(lsum[h], 16);
    lsum[h] += __shfl_xor(lsum[h], 32);
  }
  for (int h = 0; h < 2; h++)
    for (int r = 0; r < 4; r++) {
      float linv = 1.0f / __shfl(lsum[h], quad * 4 + r);
      int qg = qbase + h * 16 + quad * 4 + r;
      for (int nt = 0; nt < 4; nt++) {
        int d = nt * 16 + l16;
        ao[(size_t)bh * 131072 + (size_t)qg * 64 + d] = __float2bfloat16(o[h][nt][r] * linv);
      }
    }
}

// ---------------------------------------------------------------------------
// out = LN(a + xres); unbiased std (ddof=1), /(std + 1e-12). One block / row.
// Per-operand dtype flags (fp32 or bf16). gamma/beta fp32. fp32 math.
// Safe for out == a (reads precede barrier; writes follow).
// ---------------------------------------------------------------------------
__global__ __launch_bounds__(256) void ln_resid(
    const void* __restrict__ a, const void* __restrict__ xres,
    const float* __restrict__ gamma, const float* __restrict__ beta,
    void* __restrict__ out, int a_f32, int x_f32, int out_f32) {
  __shared__ float red[8];
  const int row = blockIdx.x, tid = threadIdx.x;
  const int w = tid >> 6, lane = tid & 63;
  const size_t base = (size_t)row * 1024;
  float v[4]; float sum = 0.f, ss = 0.f;
  for (int i = 0; i < 4; i++) {
    int c = tid + i * 256;
    float av = a_f32 ? ((const float*)a)[base + c] : b2f(((const short*)a)[base + c]);
    float xv = x_f32 ? ((const float*)xres)[base + c] : b2f(((const short*)xres)[base + c]);
    v[i] = av + xv;
    sum += v[i]; ss += v[i] * v[i];
  }
  for (int off = 1; off < 64; off <<= 1) {
    sum += __shfl_xor(sum, off);
    ss  += __shfl_xor(ss, off);
  }
  if (lane == 0) { red[w * 2] = sum; red[w * 2 + 1] = ss; }
  __syncthreads();
  sum = red[0] + red[2] + red[4] + red[6];
  ss  = red[1] + red[3] + red[5] + red[7];
  float mean = sum * (1.0f / 1024.0f);
  float var = (ss - 1024.0f * mean * mean) * (1.0f / 1023.0f);
  var = fmaxf(var, 0.f);
  float rden = 1.0f / (sqrtf(var) + 1e-12f);
  for (int i = 0; i < 4; i++) {
    int c = tid + i * 256;
    float y = gamma[c] * ((v[i] - mean) * rden) + beta[c];
    if (out_f32) ((float*)out)[base + c] = y;
    else         ((short*)out)[base + c] = f2b(y);
  }
}

// out(bf16)[c*R + r] = in(f32)[r*C + c]; R,C % 32 == 0. block (32,8),
// grid (C/32, R/32).
__global__ __launch_bounds__(256) void transpose_k(
    const float* __restrict__ in, bf16* __restrict__ out, int R, int C) {
  __shared__ short t[32][33];
  const int tx = threadIdx.x, ty = threadIdx.y;
  const int cb = blockIdx.x * 32, rb = blockIdx.y * 32;
  for (int j = 0; j < 4; j++)
    t[ty + j * 8][tx] = f2b(in[(size_t)(rb + ty + j * 8) * C + cb + tx]);
  __syncthreads();
  for (int j = 0; j < 4; j++)
    ((short*)out)[(size_t)(cb + ty + j * 8) * R + rb + tx] = t[tx][ty + j * 8];
}

__global__ __launch_bounds__(256) void concat3(
    const float* __restrict__ a, const float* __restrict__ b,
    const float* __restrict__ c, float* __restrict__ out) {
  int i = blockIdx.x * 256 + threadIdx.x;  // grid 12 -> 3072
  float v;
  if (i < 1024)       v = a[i];
  else if (i < 2048)  v = b[i - 1024];
  else                v = c[i - 2048];
  out[i] = v;
}

// fp32 -> bf16 elementwise cast, 4 elems/thread, n % 1024 == 0.
__global__ __launch_bounds__(256) void cast_f32_bf16(
    const float* __restrict__ in, bf16* __restrict__ out) {
  int i0 = (blockIdx.x * 256 + threadIdx.x) * 4;
  float4 f = *reinterpret_cast<const float4*>(in + i0);
  short* o = (short*)out + i0;
  o[0] = f2b(f.x); o[1] = f2b(f.y); o[2] = f2b(f.z); o[3] = f2b(f.w);
}

// ---------------------------------------------------------------------------
extern "C" void kernel_launch(void* const* d_in, const int* in_sizes, int n_in,
                              void* d_out, int out_size, void* d_ws, size_t ws_size,
                              hipStream_t stream) {
  (void)in_sizes; (void)n_in; (void)out_size; (void)ws_size;
  const float* x    = (const float*)d_in[0];
  const int*   mask = (const int*)d_in[1];
  const float* wq_w = (const float*)d_in[2];
  const float* wq_b = (const float*)d_in[3];
  const float* wk_w = (const float*)d_in[4];
  const float* wk_b = (const float*)d_in[5];
  const float* wv_w = (const float*)d_in[6];
  const float* wv_b = (const float*)d_in[7];
  const float* wo_w = (const float*)d_in[8];
  const float* wo_b = (const float*)d_in[9];
  const float* g1   = (const float*)d_in[10];
  const float* be1  = (const float*)d_in[11];
  const float* f1w  = (const float*)d_in[12];
  const float* f1b  = (const float*)d_in[13];
  const float* f2w  = (const float*)d_in[14];
  const float* f2b_ = (const float*)d_in[15];
  const float* g2   = (const float*)d_in[16];
  const float* be2  = (const float*)d_in[17];
  float* out = (float*)d_out;
  char* ws = (char*)d_ws;

  // ws layout (peak 48 MiB, time-shared):
  //  [0,24M)   QKV (ph2-3) -> PROJ [0,8M) (ph4-5) -> H [0,32M) (ph6-7)
  //  [24M,32M) Xbf (ph1-2) -> AO (ph3-4)
  //  [32M,40M) X1  (ph5-8)
  //  [40M,48M) WT  (transposed weights, per-phase)  + BQKV fp32 tail
  bf16*  QKV  = (bf16*)(ws + 0);
  bf16*  Xbf  = (bf16*)(ws + 25165824);
  bf16*  AO   = (bf16*)(ws + 25165824);
  bf16*  PROJ = (bf16*)(ws + 0);
  bf16*  H    = (bf16*)(ws + 0);
  bf16*  X1   = (bf16*)(ws + 33554432);
  bf16*  WT   = (bf16*)(ws + 41943040);
  float* BQKV = (float*)(ws + 48234496);

  dim3 tb(32, 8);
  // phase 1: casts + QKV weights
  cast_f32_bf16<<<dim3(4096), dim3(256), 0, stream>>>(x, Xbf);
  transpose_k<<<dim3(32, 32), tb, 0, stream>>>(wq_w, WT, 1024, 1024);
  transpose_k<<<dim3(32, 32), tb, 0, stream>>>(wk_w, WT + 1024 * 1024, 1024, 1024);
  transpose_k<<<dim3(32, 32), tb, 0, stream>>>(wv_w, WT + 2 * 1024 * 1024, 1024, 1024);
  concat3<<<dim3(12), dim3(256), 0, stream>>>(wq_b, wk_b, wv_b, BQKV);
  // phase 2: fused QKV projection [4096,1024]@[3072,1024]^T -> bf16
  gemm_bt<<<dim3(24, 32), dim3(256), 0, stream>>>(Xbf, WT, BQKV, QKV, 4096, 3072, 1024, 3072, 0, 0);
  // phase 3: attention (512 blocks: 16 q-blocks x 32 bh)
  attn_kernel<<<dim3(16, 32), dim3(256), 0, stream>>>(QKV, mask, AO);
  // phase 4: output projection
  transpose_k<<<dim3(32, 32), tb, 0, stream>>>(wo_w, WT, 1024, 1024);
  gemm_bt<<<dim3(8, 32), dim3(256), 0, stream>>>(AO, WT, wo_b, PROJ, 4096, 1024, 1024, 1024, 0, 0);
  // phase 5: LN1 (xres = original fp32 x)
  ln_resid<<<dim3(4096), dim3(256), 0, stream>>>(PROJ, x, g1, be1, X1, 0, 1, 0);
  // phase 6: FFN up
  transpose_k<<<dim3(128, 32), tb, 0, stream>>>(f1w, WT, 1024, 4096);
  gemm_bt<<<dim3(32, 32), dim3(256), 0, stream>>>(X1, WT, f1b, H, 4096, 4096, 1024, 4096, 1, 0);
  // phase 7: FFN down, fp32 straight into d_out
  transpose_k<<<dim3(32, 128), tb, 0, stream>>>(f2w, WT, 4096, 1024);
  gemm_bt<<<dim3(8, 32), dim3(256), 0, stream>>>(H, WT, f2b_, out, 4096, 1024, 4096, 1024, 0, 1);
  // phase 8: LN2 in-place on d_out (fp32 a, bf16 xres, fp32 out)
  ln_resid<<<dim3(4096), dim3(256), 0, stream>>>(out, X1, g2, be2, out, 1, 0, 1);
}

// Round 8
// 473.575 us; speedup vs baseline: 1.1913x; 1.0011x over previous
//
#include <hip/hip_runtime.h>
#include <hip/hip_bf16.h>
#include <cstdint>
#include <cstddef>

using bf16 = __hip_bfloat16;
typedef __attribute__((ext_vector_type(8))) short short8v;   // MFMA A/B frag: 8 bf16
typedef __attribute__((ext_vector_type(4))) short short4v;   // 4 bf16 (b64 store)
typedef __attribute__((ext_vector_type(4))) float float4v;   // MFMA C/D frag

__device__ inline float b2f(short s) {
  union { float f; uint32_t u; } z; z.u = ((uint32_t)(uint16_t)s) << 16; return z.f;
}
__device__ inline short f2b(float f) {
  bf16 h = __float2bfloat16(f);
  return *reinterpret_cast<short*>(&h);
}

typedef const __attribute__((address_space(1))) uint32_t* gas1p;
typedef __attribute__((address_space(3))) uint32_t* las3p;
__device__ inline void gload_lds16(const void* g, void* l) {
  __builtin_amdgcn_global_load_lds((gas1p)g, (las3p)l, 16, 0, 0);
}

// ---------------------------------------------------------------------------
// GEMM (m97 structure): C = A @ Bt^T + bias, optional ReLU. For grids >= 3
// blocks/CU (QKV, FF1) where implicit wave overlap hides the barrier drain.
// ---------------------------------------------------------------------------
__global__ __launch_bounds__(256) void gemm_bt(
    const bf16* __restrict__ A, const bf16* __restrict__ Bt,
    const float* __restrict__ bias, void* __restrict__ C,
    int M, int N, int K, int ldc, int relu_mode, int out_f32) {
  __shared__ __align__(16) bf16 As[128 * 32];
  __shared__ __align__(16) bf16 Bs[128 * 32];
  const int tid = threadIdx.x;
  const int w = tid >> 6, lane = tid & 63;
  const int quad = lane >> 4, l16 = lane & 15;
  const int wrow = (w >> 1) * 64, wcol = (w & 1) * 64;
  const int mbase = blockIdx.y * 128, nbase = blockIdx.x * 128;
  const int c = w * 128 + lane;            // chunk ids c and c+64
  const int row0 = c >> 2, p0 = c & 3;
  const int row1 = (c + 64) >> 2, p1 = (c + 64) & 3;

  float4v acc[4][4];
  for (int i = 0; i < 4; i++)
    for (int j = 0; j < 4; j++) acc[i][j] = (float4v){0.f, 0.f, 0.f, 0.f};

  for (int k0 = 0; k0 < K; k0 += 32) {
    __syncthreads();  // prev iter's ds_reads done before restage
    gload_lds16(A + (size_t)(mbase + row0) * K + k0 + p0 * 8, (char*)As + w * 2048);
    gload_lds16(A + (size_t)(mbase + row1) * K + k0 + p1 * 8, (char*)As + w * 2048 + 1024);
    gload_lds16(Bt + (size_t)(nbase + row0) * K + k0 + p0 * 8, (char*)Bs + w * 2048);
    gload_lds16(Bt + (size_t)(nbase + row1) * K + k0 + p1 * 8, (char*)Bs + w * 2048 + 1024);
    __syncthreads();  // vmcnt drained -> tiles valid

    short8v a[4], b[4];
    for (int mt = 0; mt < 4; mt++)
      a[mt] = *reinterpret_cast<const short8v*>(As + (wrow + mt * 16 + l16) * 32 + quad * 8);
    for (int nt = 0; nt < 4; nt++)
      b[nt] = *reinterpret_cast<const short8v*>(Bs + (wcol + nt * 16 + l16) * 32 + quad * 8);
    for (int mt = 0; mt < 4; mt++)
      for (int nt = 0; nt < 4; nt++)
        acc[mt][nt] = __builtin_amdgcn_mfma_f32_16x16x32_bf16(a[mt], b[nt], acc[mt][nt], 0, 0, 0);
  }

  // epilogue: D row = quad*4+reg, col = lane&15
  for (int nt = 0; nt < 4; nt++) {
    int col = nbase + wcol + nt * 16 + l16;
    float bv = bias[col];
    for (int mt = 0; mt < 4; mt++) {
      int row = mbase + wrow + mt * 16 + quad * 4;
      for (int r = 0; r < 4; r++) {
        float v = acc[mt][nt][r] + bv;
        if (relu_mode) v = fmaxf(v, 0.f);
        size_t idx = (size_t)(row + r) * ldc + col;
        if (out_f32) ((float*)C)[idx] = v;
        else         ((short*)C)[idx] = f2b(v);
      }
    }
  }
}

// ---------------------------------------------------------------------------
// Pipelined split-K GEMM for grid-limited shapes (WO, FF2; 1-2 blocks/CU):
// LDS double-buffered, next K-tile prefetched into registers at iter top,
// written to the other buffer after MFMA — ONE barrier per iter (same
// transform that fixed attn). blockIdx.z selects a K-slice of length k_len;
// partial sums atomicAdd into fp32 C (bias pre-initialized by bias_init).
// ---------------------------------------------------------------------------
__global__ __launch_bounds__(256) void gemm_pipe(
    const bf16* __restrict__ A, const bf16* __restrict__ Bt,
    float* __restrict__ C, int K, int ldc, int k_len) {
  __shared__ __align__(16) bf16 As[2][128 * 32];
  __shared__ __align__(16) bf16 Bs[2][128 * 32];
  const int tid = threadIdx.x;
  const int w = tid >> 6, lane = tid & 63;
  const int quad = lane >> 4, l16 = lane & 15;
  const int wrow = (w >> 1) * 64, wcol = (w & 1) * 64;
  const int mbase = blockIdx.y * 128, nbase = blockIdx.x * 128;
  const int srow = tid >> 1, scol = (tid & 1) * 16;  // 16 elems (2xb128) / thread

  const bf16* ag = A + (size_t)(mbase + srow) * K + blockIdx.z * k_len + scol;
  const bf16* bg = Bt + (size_t)(nbase + srow) * K + blockIdx.z * k_len + scol;

  float4v acc[4][4];
  for (int i = 0; i < 4; i++)
    for (int j = 0; j < 4; j++) acc[i][j] = (float4v){0.f, 0.f, 0.f, 0.f};

  // prologue: tile 0 -> LDS[0]
  {
    short8v a0 = *reinterpret_cast<const short8v*>(ag);
    short8v a1 = *reinterpret_cast<const short8v*>(ag + 8);
    short8v b0 = *reinterpret_cast<const short8v*>(bg);
    short8v b1 = *reinterpret_cast<const short8v*>(bg + 8);
    *reinterpret_cast<short8v*>(&As[0][srow * 32 + scol])     = a0;
    *reinterpret_cast<short8v*>(&As[0][srow * 32 + scol + 8]) = a1;
    *reinterpret_cast<short8v*>(&Bs[0][srow * 32 + scol])     = b0;
    *reinterpret_cast<short8v*>(&Bs[0][srow * 32 + scol + 8]) = b1;
  }
  __syncthreads();

  const int KT = k_len >> 5;
  for (int kt = 0; kt < KT; kt++) {
    const int pb = kt & 1;
    short8v na0, na1, nb0, nb1;
    const bool more = (kt + 1 < KT);
    if (more) {
      const bf16* ap = ag + (kt + 1) * 32;
      const bf16* bp = bg + (kt + 1) * 32;
      na0 = *reinterpret_cast<const short8v*>(ap);
      na1 = *reinterpret_cast<const short8v*>(ap + 8);
      nb0 = *reinterpret_cast<const short8v*>(bp);
      nb1 = *reinterpret_cast<const short8v*>(bp + 8);
    }

    short8v a[4], b[4];
    for (int mt = 0; mt < 4; mt++)
      a[mt] = *reinterpret_cast<const short8v*>(&As[pb][(wrow + mt * 16 + l16) * 32 + quad * 8]);
    for (int nt = 0; nt < 4; nt++)
      b[nt] = *reinterpret_cast<const short8v*>(&Bs[pb][(wcol + nt * 16 + l16) * 32 + quad * 8]);
    for (int mt = 0; mt < 4; mt++)
      for (int nt = 0; nt < 4; nt++)
        acc[mt][nt] = __builtin_amdgcn_mfma_f32_16x16x32_bf16(a[mt], b[nt], acc[mt][nt], 0, 0, 0);

    if (more) {
      *reinterpret_cast<short8v*>(&As[1 - pb][srow * 32 + scol])     = na0;
      *reinterpret_cast<short8v*>(&As[1 - pb][srow * 32 + scol + 8]) = na1;
      *reinterpret_cast<short8v*>(&Bs[1 - pb][srow * 32 + scol])     = nb0;
      *reinterpret_cast<short8v*>(&Bs[1 - pb][srow * 32 + scol + 8]) = nb1;
    }
    __syncthreads();
  }

  // epilogue: partial-sum atomicAdd (C pre-initialized with bias)
  for (int nt = 0; nt < 4; nt++) {
    int col = nbase + wcol + nt * 16 + l16;
    for (int mt = 0; mt < 4; mt++) {
      int row = mbase + wrow + mt * 16 + quad * 4;
      for (int r = 0; r < 4; r++)
        atomicAdd(&C[(size_t)(row + r) * ldc + col], acc[mt][nt][r]);
    }
  }
}

// C[row, 0..N) = bias[0..N), fp32. grid = rows, block 256, N = 1024.
__global__ __launch_bounds__(256) void bias_init(
    const float* __restrict__ bias, float* __restrict__ C) {
  int c = threadIdx.x * 4;
  float4 bv = *reinterpret_cast<const float4*>(bias + c);
  *reinterpret_cast<float4*>(C + (size_t)blockIdx.x * 1024 + c) = bv;
}

// ---------------------------------------------------------------------------
// Flash attention v4 (round-7 validated): 32 q-rows/wave, 512 blocks,
// register-prefetch pipeline, one barrier/iter.
// ---------------------------------------------------------------------------
__global__ __launch_bounds__(256) void attn_kernel(
    const bf16* __restrict__ qkv, const int* __restrict__ mask,
    bf16* __restrict__ ao) {
  __shared__ __align__(16) short Vt[2][64 * 40];   // [buf][d][kv], pitch 40
  __shared__ __align__(16) short Pbuf[4][32 * 40]; // per-wave [q][kv], pitch 40

  const int tid = threadIdx.x;
  const int w = tid >> 6, lane = tid & 63;
  const int quad = lane >> 4, l16 = lane & 15;
  const int bh = blockIdx.y, b = bh >> 4;
  const int row0 = bh * 128;                 // row base in qkv [4096,3072]
  const int qbase = blockIdx.x * 128 + w * 32;  // wave's 32 q rows
  const int vr = tid & 31, vdb = (tid >> 5) * 8;

  short8v aq[2][2];
  for (int h = 0; h < 2; h++)
    for (int dh = 0; dh < 2; dh++) {
      int local = (qbase + h * 16 + l16) * 64 + dh * 32 + quad * 8;
      aq[h][dh] = *reinterpret_cast<const short8v*>(
          qkv + (size_t)(row0 + (local >> 10)) * 3072 + (local & 1023));
    }

  const bf16* pk[2][2];
  for (int s = 0; s < 2; s++)
    for (int dh = 0; dh < 2; dh++) {
      int local = (s * 16 + l16) * 64 + dh * 32 + quad * 8;
      pk[s][dh] = qkv + (size_t)(row0 + (local >> 10)) * 3072 + (local & 1023) + 1024;
    }
  const bf16* pv;
  {
    int local = vr * 64 + vdb;
    pv = qkv + (size_t)(row0 + (local >> 10)) * 3072 + (local & 1023) + 2048;
  }
  const int* pm = mask + b * 2048 + quad * 4;

  float4v o[2][4];
  for (int h = 0; h < 2; h++)
    for (int nt = 0; nt < 4; nt++) o[h][nt] = (float4v){0.f, 0.f, 0.f, 0.f};
  float lsum[2] = {0.f, 0.f};

  short8v kcur[2][2], vcur;
  vcur = *reinterpret_cast<const short8v*>(pv);
  for (int s = 0; s < 2; s++)
    for (int dh = 0; dh < 2; dh++)
      kcur[s][dh] = *reinterpret_cast<const short8v*>(pk[s][dh]);
  int4 mc0 = *reinterpret_cast<const int4*>(pm);
  int4 mc1 = *reinterpret_cast<const int4*>(pm + 16);
  pv += 6144; pm += 32;
  for (int s = 0; s < 2; s++)
    for (int dh = 0; dh < 2; dh++) pk[s][dh] += 6144;
  {
    short* vt = &Vt[0][0];
    for (int j = 0; j < 8; j++) vt[(vdb + j) * 40 + vr] = vcur[j];
  }
  __syncthreads();

  for (int it = 0; it < 64; it++) {
    const int pb = it & 1;
    short8v knext[2][2], vnext;
    int4 mn0, mn1;
    if (it < 63) {
      vnext = *reinterpret_cast<const short8v*>(pv);
      for (int s = 0; s < 2; s++)
        for (int dh = 0; dh < 2; dh++)
          knext[s][dh] = *reinterpret_cast<const short8v*>(pk[s][dh]);
      mn0 = *reinterpret_cast<const int4*>(pm);
      mn1 = *reinterpret_cast<const int4*>(pm + 16);
      pv += 6144; pm += 32;
      for (int s = 0; s < 2; s++)
        for (int dh = 0; dh < 2; dh++) pk[s][dh] += 6144;
    }

    float4v st[2][2];
    for (int s = 0; s < 2; s++)
      for (int h = 0; h < 2; h++) {
        float4v t = (float4v){0.f, 0.f, 0.f, 0.f};
        t = __builtin_amdgcn_mfma_f32_16x16x32_bf16(kcur[s][0], aq[h][0], t, 0, 0, 0);
        t = __builtin_amdgcn_mfma_f32_16x16x32_bf16(kcur[s][1], aq[h][1], t, 0, 0, 0);
        st[s][h] = t;
      }

    for (int h = 0; h < 2; h++)
      for (int s = 0; s < 2; s++) {
        int4 mv = s ? mc1 : mc0;
        int mm[4] = {mv.x, mv.y, mv.z, mv.w};
        short4v pkv;
        for (int r = 0; r < 4; r++) {
          float y = st[s][h][r] * 0.180336880f;     // (1/8)*log2(e)
          y = fminf(fmaxf(y, -43.3f), 43.3f);       // garbage guard only
          y = (mm[r] == 0) ? -1.4427e-12f : y;      // faithful mask semantics
          float e = __builtin_amdgcn_exp2f(y);
          lsum[h] += e;
          pkv[r] = f2b(e);
        }
        *reinterpret_cast<short4v*>(&Pbuf[w][(h * 16 + l16) * 40 + s * 16 + quad * 4]) = pkv;
      }
    short8v pf[2];
    for (int h = 0; h < 2; h++)
      pf[h] = *reinterpret_cast<const short8v*>(&Pbuf[w][(h * 16 + l16) * 40 + quad * 8]);
    for (int nt = 0; nt < 4; nt++) {
      short8v bv = *reinterpret_cast<const short8v*>(&Vt[pb][(nt * 16 + l16) * 40 + quad * 8]);
      for (int h = 0; h < 2; h++)
        o[h][nt] = __builtin_amdgcn_mfma_f32_16x16x32_bf16(pf[h], bv, o[h][nt], 0, 0, 0);
    }

    if (it < 63) {
      short* vt = &Vt[1 - pb][0];
      for (int j = 0; j < 8; j++) vt[(vdb + j) * 40 + vr] = vnext[j];
      for (int s = 0; s < 2; s++)
        for (int dh = 0; dh < 2; dh++) kcur[s][dh] = knext[s][dh];
      mc0 = mn0; mc1 = mn1;
    }
    __syncthreads();
  }

  for (int h = 0; h < 2; h++) {
    lsum[h] += __shfl_xor(lsum[h], 16);
    lsum[h] += __shfl_xor(lsum[h], 32);
  }
  for (int h = 0; h < 2; h++)
    for (int r = 0; r < 4; r++) {
      float linv = 1.0f / __shfl(lsum[h], quad * 4 + r);
      int qg = qbase + h * 16 + quad * 4 + r;
      for (int nt = 0; nt < 4; nt++) {
        int d = nt * 16 + l16;
        ao[(size_t)bh * 131072 + (size_t)qg * 64 + d] = __float2bfloat16(o[h][nt][r] * linv);
      }
    }
}

// ---------------------------------------------------------------------------
// out = LN(a + xres); unbiased std (ddof=1), /(std + 1e-12). One block / row.
// ---------------------------------------------------------------------------
__global__ __launch_bounds__(256) void ln_resid(
    const void* __restrict__ a, const void* __restrict__ xres,
    const float* __restrict__ gamma, const float* __restrict__ beta,
    void* __restrict__ out, int a_f32, int x_f32, int out_f32) {
  __shared__ float red[8];
  const int row = blockIdx.x, tid = threadIdx.x;
  const int w = tid >> 6, lane = tid & 63;
  const size_t base = (size_t)row * 1024;
  float v[4]; float sum = 0.f, ss = 0.f;
  for (int i = 0; i < 4; i++) {
    int c = tid + i * 256;
    float av = a_f32 ? ((const float*)a)[base + c] : b2f(((const short*)a)[base + c]);
    float xv = x_f32 ? ((const float*)xres)[base + c] : b2f(((const short*)xres)[base + c]);
    v[i] = av + xv;
    sum += v[i]; ss += v[i] * v[i];
  }
  for (int off = 1; off < 64; off <<= 1) {
    sum += __shfl_xor(sum, off);
    ss  += __shfl_xor(ss, off);
  }
  if (lane == 0) { red[w * 2] = sum; red[w * 2 + 1] = ss; }
  __syncthreads();
  sum = red[0] + red[2] + red[4] + red[6];
  ss  = red[1] + red[3] + red[5] + red[7];
  float mean = sum * (1.0f / 1024.0f);
  float var = (ss - 1024.0f * mean * mean) * (1.0f / 1023.0f);
  var = fmaxf(var, 0.f);
  float rden = 1.0f / (sqrtf(var) + 1e-12f);
  for (int i = 0; i < 4; i++) {
    int c = tid + i * 256;
    float y = gamma[c] * ((v[i] - mean) * rden) + beta[c];
    if (out_f32) ((float*)out)[base + c] = y;
    else         ((short*)out)[base + c] = f2b(y);
  }
}

// out(bf16)[c*R + r] = in(f32)[r*C + c]; R,C % 32 == 0.
__global__ __launch_bounds__(256) void transpose_k(
    const float* __restrict__ in, bf16* __restrict__ out, int R, int C) {
  __shared__ short t[32][33];
  const int tx = threadIdx.x, ty = threadIdx.y;
  const int cb = blockIdx.x * 32, rb = blockIdx.y * 32;
  for (int j = 0; j < 4; j++)
    t[ty + j * 8][tx] = f2b(in[(size_t)(rb + ty + j * 8) * C + cb + tx]);
  __syncthreads();
  for (int j = 0; j < 4; j++)
    ((short*)out)[(size_t)(cb + ty + j * 8) * R + rb + tx] = t[tx][ty + j * 8];
}

__global__ __launch_bounds__(256) void concat3(
    const float* __restrict__ a, const float* __restrict__ b,
    const float* __restrict__ c, float* __restrict__ out) {
  int i = blockIdx.x * 256 + threadIdx.x;  // grid 12 -> 3072
  float v;
  if (i < 1024)       v = a[i];
  else if (i < 2048)  v = b[i - 1024];
  else                v = c[i - 2048];
  out[i] = v;
}

__global__ __launch_bounds__(256) void cast_f32_bf16(
    const float* __restrict__ in, bf16* __restrict__ out) {
  int i0 = (blockIdx.x * 256 + threadIdx.x) * 4;
  float4 f = *reinterpret_cast<const float4*>(in + i0);
  short* o = (short*)out + i0;
  o[0] = f2b(f.x); o[1] = f2b(f.y); o[2] = f2b(f.z); o[3] = f2b(f.w);
}

// ---------------------------------------------------------------------------
extern "C" void kernel_launch(void* const* d_in, const int* in_sizes, int n_in,
                              void* d_out, int out_size, void* d_ws, size_t ws_size,
                              hipStream_t stream) {
  (void)in_sizes; (void)n_in; (void)out_size; (void)ws_size;
  const float* x    = (const float*)d_in[0];
  const int*   mask = (const int*)d_in[1];
  const float* wq_w = (const float*)d_in[2];
  const float* wq_b = (const float*)d_in[3];
  const float* wk_w = (const float*)d_in[4];
  const float* wk_b = (const float*)d_in[5];
  const float* wv_w = (const float*)d_in[6];
  const float* wv_b = (const float*)d_in[7];
  const float* wo_w = (const float*)d_in[8];
  const float* wo_b = (const float*)d_in[9];
  const float* g1   = (const float*)d_in[10];
  const float* be1  = (const float*)d_in[11];
  const float* f1w  = (const float*)d_in[12];
  const float* f1b  = (const float*)d_in[13];
  const float* f2w  = (const float*)d_in[14];
  const float* f2b_ = (const float*)d_in[15];
  const float* g2   = (const float*)d_in[16];
  const float* be2  = (const float*)d_in[17];
  float* out = (float*)d_out;
  char* ws = (char*)d_ws;

  // ws layout (peak 48 MiB, time-shared):
  //  [0,24M)   QKV (ph2-3) -> PROJ fp32 [0,16M) (ph4-5) -> H [0,32M) (ph6-7)
  //  [24M,32M) Xbf (ph1-2) -> AO (ph3-4)
  //  [32M,40M) X1  (ph5-8)
  //  [40M,48M) WT  (transposed weights, per-phase)  + BQKV fp32 tail
  bf16*  QKV  = (bf16*)(ws + 0);
  bf16*  Xbf  = (bf16*)(ws + 25165824);
  bf16*  AO   = (bf16*)(ws + 25165824);
  float* PROJ = (float*)(ws + 0);
  bf16*  H    = (bf16*)(ws + 0);
  bf16*  X1   = (bf16*)(ws + 33554432);
  bf16*  WT   = (bf16*)(ws + 41943040);
  float* BQKV = (float*)(ws + 48234496);

  dim3 tb(32, 8);
  // phase 1: casts + QKV weights
  cast_f32_bf16<<<dim3(4096), dim3(256), 0, stream>>>(x, Xbf);
  transpose_k<<<dim3(32, 32), tb, 0, stream>>>(wq_w, WT, 1024, 1024);
  transpose_k<<<dim3(32, 32), tb, 0, stream>>>(wk_w, WT + 1024 * 1024, 1024, 1024);
  transpose_k<<<dim3(32, 32), tb, 0, stream>>>(wv_w, WT + 2 * 1024 * 1024, 1024, 1024);
  concat3<<<dim3(12), dim3(256), 0, stream>>>(wq_b, wk_b, wv_b, BQKV);
  // phase 2: fused QKV projection [4096,1024]@[3072,1024]^T -> bf16
  gemm_bt<<<dim3(24, 32), dim3(256), 0, stream>>>(Xbf, WT, BQKV, QKV, 4096, 3072, 1024, 3072, 0, 0);
  // phase 3: attention (512 blocks: 16 q-blocks x 32 bh)
  attn_kernel<<<dim3(16, 32), dim3(256), 0, stream>>>(QKV, mask, AO);
  // phase 4: output projection — pipelined split-K=2, fp32 atomic into PROJ
  transpose_k<<<dim3(32, 32), tb, 0, stream>>>(wo_w, WT, 1024, 1024);
  bias_init<<<dim3(4096), dim3(256), 0, stream>>>(wo_b, PROJ);
  gemm_pipe<<<dim3(8, 32, 2), dim3(256), 0, stream>>>(AO, WT, PROJ, 1024, 1024, 512);
  // phase 5: LN1 (a = PROJ fp32, xres = original fp32 x)
  ln_resid<<<dim3(4096), dim3(256), 0, stream>>>(PROJ, x, g1, be1, X1, 1, 1, 0);
  // phase 6: FFN up (m97 gemm, 1024 blocks)
  transpose_k<<<dim3(128, 32), tb, 0, stream>>>(f1w, WT, 1024, 4096);
  gemm_bt<<<dim3(32, 32), dim3(256), 0, stream>>>(X1, WT, f1b, H, 4096, 4096, 1024, 4096, 1, 0);
  // phase 7: FFN down — pipelined split-K=2, fp32 atomic straight into d_out
  transpose_k<<<dim3(32, 128), tb, 0, stream>>>(f2w, WT, 4096, 1024);
  bias_init<<<dim3(4096), dim3(256), 0, stream>>>(f2b_, out);
  gemm_pipe<<<dim3(8, 32, 2), dim3(256), 0, stream>>>(H, WT, out, 4096, 1024, 2048);
  // phase 8: LN2 in-place on d_out (fp32 a, bf16 xres, fp32 out)
  ln_resid<<<dim3(4096), dim3(256), 0, stream>>>(out, X1, g2, be2, out, 1, 0, 1);
}